// Round 13
// baseline (180.024 us; speedup 1.0000x reference)
//
#include <hip/hip_runtime.h>
#include <stdint.h>

#define HID 30
#define NCLS 10
#define SEQ 784
#define NBATCH 16384
#define TCH 112      // time steps per LDS stage
#define NSTAGE 7     // 7 * 112 = 784
#define XPAD 116     // padded LDS row stride in floats

typedef _Float16 f16x8 __attribute__((ext_vector_type(8)));
typedef _Float16 f16x2 __attribute__((ext_vector_type(2)));
typedef float f32x4 __attribute__((ext_vector_type(4)));
typedef uint32_t u32x4 __attribute__((ext_vector_type(4)));

static __device__ __forceinline__ f16x8 mkfrag16(uint32_t a, uint32_t b, uint32_t c, uint32_t d) {
    u32x4 t = {a, b, c, d};
    return __builtin_bit_cast(f16x8, t);
}

static __device__ __forceinline__ uint32_t pkf16(_Float16 lo, _Float16 hi) {
    f16x2 v = {lo, hi};
    return __builtin_bit_cast(uint32_t, v);
}

// RNE f32->f16 pair pack. RNE is REQUIRED on the recurrent path (R8: RTZ+bias
// compensation diverged 100x).
static __device__ __forceinline__ uint32_t pk_rne(float a, float b) {
    return pkf16((_Float16)a, (_Float16)b);
}

// RTZ fine for one-shot x injection (non-recurrent)
static __device__ __forceinline__ uint32_t pkrtz(float a, float b) {
    return __builtin_bit_cast(uint32_t, __builtin_amdgcn_cvt_pkrtz(a, b));
}

// packed modReLU on an f16 pair: h = sign(z) * max(|z| + b, 0).
// v_pk_max_f16(t, +0) never returns -0, so t's sign bits are already clear;
// (z & sign) | t fuses to v_and_or_b32.
static __device__ __forceinline__ uint32_t modrelu_pk(uint32_t z, uint32_t bp) {
    const f16x2 zero2 = {(_Float16)0.f, (_Float16)0.f};
    f16x2 t = __builtin_bit_cast(f16x2, z & 0x7FFF7FFFu) + __builtin_bit_cast(f16x2, bp);
    t = __builtin_elementwise_max(t, zero2);
    return (z & 0x80008000u) | __builtin_bit_cast(uint32_t, t);
}

static __device__ __forceinline__ uint32_t pkmax(uint32_t a, uint32_t b) {
    return __builtin_bit_cast(uint32_t,
        __builtin_elementwise_max(__builtin_bit_cast(f16x2, a), __builtin_bit_cast(f16x2, b)));
}

static __device__ __forceinline__ uint32_t scale_mul(uint32_t v, uint32_t sc32) {
    return __builtin_bit_cast(uint32_t,
        __builtin_bit_cast(f16x2, v) * __builtin_bit_cast(f16x2, sc32));
}

// R18 = exact revert to the round-10 R15 source (110.3us/dispatch, 179.3us
// bench, PASSED). R17's "bit-identical" u32x4-state refactor FAILED numerics
// (absmax 2.1e32 vs 1.7e30): per-element writes into a reference-captured
// ext_vector miscompile vs the SROA'd scalar array. SESSION RULE: hot
// recurrent state must be plain named scalars/arrays with constant indices --
// nothing address-taken (R9), nothing vector-subscript-written (R17).
// R15 structure: boundary blob (butterfly finish -> pend -> fac -> next-window
// x-gen) dissolved into the second do8's MFMA shadow; modReLU 4-op form.
__launch_bounds__(64, 1)
__global__ void rnn_scan_kernel(const float* __restrict__ inp,
                                const float* __restrict__ W_ih,
                                const float* __restrict__ W_hh,
                                const float* __restrict__ b_mod,
                                const float* __restrict__ W_lin,
                                const float* __restrict__ b_lin,
                                float* __restrict__ out)
{
    __shared__ __align__(16) float xs_lds[16 * XPAD];

    const int lane = threadIdx.x;   // one wave per block
    const int q = lane >> 4;        // k-quad: lane holds k = 8q..8q+7 of A/B frags
    const int n = lane & 15;        // batch column within the wave's 16-batch tile
    const int b0 = blockIdx.x * 16;

    // ---- A fragments: W_aug [32x32], row-permuted so D->B is lane-local ----
    // W_aug[i][j] = W_hh[i][j] (i,j<30); W_aug[i][30] = W_ih[i]; else 0.
    // A = Ah + Am (2-way f16 RNE split, ~21-bit; REQUIRED per R16 failure)
    const int i1 = 8 * (n >> 2) + (n & 3);
    const int i2 = i1 + 4;

    uint32_t a1h[4], a1m[4], a2h[4], a2m[4];
    #pragma unroll
    for (int p = 0; p < 4; ++p) {
        _Float16 h1[2], m1[2], h2[2], m2[2];
        #pragma unroll
        for (int e = 0; e < 2; ++e) {
            const int j = 8 * q + 2 * p + e;
            float w1 = 0.f, w2 = 0.f;
            if (j < HID) {
                w1 = W_hh[i1 * HID + j];
                if (i2 < HID) w2 = W_hh[i2 * HID + j];
            } else if (j == HID) {
                w1 = W_ih[i1];
                if (i2 < HID) w2 = W_ih[i2];
            }
            h1[e] = (_Float16)w1; m1[e] = (_Float16)(w1 - (float)h1[e]);
            h2[e] = (_Float16)w2; m2[e] = (_Float16)(w2 - (float)h2[e]);
        }
        a1h[p] = pkf16(h1[0], h1[1]); a1m[p] = pkf16(m1[0], m1[1]);
        a2h[p] = pkf16(h2[0], h2[1]); a2m[p] = pkf16(m2[0], m2[1]);
    }
    const f16x8 A1h = mkfrag16(a1h[0], a1h[1], a1h[2], a1h[3]);
    const f16x8 A1m = mkfrag16(a1m[0], a1m[1], a1m[2], a1m[3]);
    const f16x8 A2h = mkfrag16(a2h[0], a2h[1], a2h[2], a2h[3]);
    const f16x8 A2m = mkfrag16(a2m[0], a2m[1], a2m[2], a2m[3]);

    // b_mod packed pairs for this lane's 8 output rows (f16, scaled space b/S)
    uint32_t bSp[4];
    #pragma unroll
    for (int p = 0; p < 4; ++p) {
        const int ja = 8 * q + 2 * p;
        const int jb = ja + 1;
        const float ba = (ja < HID) ? b_mod[ja] : 0.f;
        const float bb = (jb < HID) ? b_mod[jb] : 0.f;
        bSp[p] = pk_rne(ba, bb);
    }

    // packed f16 state: hp[p] = (h[8q+2p], h[8q+2p+1]) in scaled space.
    // True h = S * h_hat, S = 2^(-xinv_e) per column. q3's hp[3] (rows 30,31 =
    // zero rows of W_aug) is dead state, reused as the x-injection slot so the
    // persistent state quad IS the MFMA B fragment.
    uint32_t hp[4] = {0u, 0u, 0u, 0u};
    int xinv_e = 0;

    const bool isq3 = (q == 3);
    const f32x4 z4 = {0.f, 0.f, 0.f, 0.f};

    // one recurrence step (R0-verbatim chained-MFMA body); xnext = the x value
    // injected into the dead slot for the NEXT step (by value, named scalar).
    auto step = [&](uint32_t xnext) {
        const f16x8 Bh = mkfrag16(hp[0], hp[1], hp[2], hp[3]);
        f32x4 d1 = __builtin_amdgcn_mfma_f32_16x16x32_f16(A1h, Bh, z4, 0, 0, 0);
        f32x4 d2 = __builtin_amdgcn_mfma_f32_16x16x32_f16(A2h, Bh, z4, 0, 0, 0);
        d1 = __builtin_amdgcn_mfma_f32_16x16x32_f16(A1m, Bh, d1, 0, 0, 0);
        d2 = __builtin_amdgcn_mfma_f32_16x16x32_f16(A2m, Bh, d2, 0, 0, 0);
        hp[0] = modrelu_pk(pk_rne(d1[0], d1[1]), bSp[0]);
        hp[1] = modrelu_pk(pk_rne(d1[2], d1[3]), bSp[1]);
        hp[2] = modrelu_pk(pk_rne(d2[0], d2[1]), bSp[2]);
        const uint32_t mr3 = modrelu_pk(pk_rne(d2[2], d2[3]), bSp[3]);
        hp[3] = isq3 ? xnext : mr3;
    };

    for (int s = 0; s < NSTAGE; ++s) {
        // ---- stage TCH steps of inputs for 16 batch rows into LDS ----
        #pragma unroll
        for (int r = 0; r < 7; ++r) {
            const int idx = r * 64 + lane;
            const int bl = idx / 28;
            const int t4 = idx % 28;
            const float4 v = *(const float4*)(inp + (size_t)(b0 + bl) * SEQ + s * TCH + t4 * 4);
            *(float4*)(&xs_lds[bl * XPAD + t4 * 4]) = v;
        }
        __syncthreads();

        const float* xrow = &xs_lds[n * XPAD];

        // ---- stage top: load + pack window-0 x (once per 112 steps) ----
        float4 xv0 = *(const float4*)(xrow);
        float4 xv1 = *(const float4*)(xrow + 4);
        float4 xw0 = *(const float4*)(xrow + 8);
        float4 xw1 = *(const float4*)(xrow + 12);

        const float fac0 = __uint_as_float((uint32_t)(127 + xinv_e) << 23);
        uint32_t xa0 = pkrtz(xv0.x * fac0, 0.f), xa1 = pkrtz(xv0.y * fac0, 0.f);
        uint32_t xa2 = pkrtz(xv0.z * fac0, 0.f), xa3 = pkrtz(xv0.w * fac0, 0.f);
        uint32_t xa4 = pkrtz(xv1.x * fac0, 0.f), xa5 = pkrtz(xv1.y * fac0, 0.f);
        uint32_t xa6 = pkrtz(xv1.z * fac0, 0.f), xa7 = pkrtz(xv1.w * fac0, 0.f);
        uint32_t yb0 = pkrtz(xw0.x * fac0, 0.f), yb1 = pkrtz(xw0.y * fac0, 0.f);
        uint32_t yb2 = pkrtz(xw0.z * fac0, 0.f), yb3 = pkrtz(xw0.w * fac0, 0.f);
        uint32_t yb4 = pkrtz(xw1.x * fac0, 0.f), yb5 = pkrtz(xw1.y * fac0, 0.f);
        uint32_t yb6 = pkrtz(xw1.z * fac0, 0.f), yb7 = pkrtz(xw1.w * fac0, 0.f);

        // prefetch window-1 raw x (consumed mid-window-0; ~10 steps of cover)
        xv0 = *(const float4*)(xrow + 16);
        xv1 = *(const float4*)(xrow + 20);
        xw0 = *(const float4*)(xrow + 24);
        xw1 = *(const float4*)(xrow + 28);

        for (int t16 = 0; t16 < 7; ++t16) {   // 7 * 16 = 112 steps per stage
            // inject step-0 x, SAMPLE max for the NEXT window (16-step
            // staleness safe: overflow needs ~2^20 growth in 16 steps,
            // measured ~2^2). Butterfly split across the window.
            hp[3] = isq3 ? xa0 : hp[3];
            uint32_t mx = pkmax(pkmax(hp[0] & 0x7FFF7FFFu, hp[1] & 0x7FFF7FFFu),
                                pkmax(hp[2] & 0x7FFF7FFFu, hp[3] & 0x7FFF7FFFu));
            const uint32_t sh1 = (uint32_t)__shfl_xor((int)mx, 16);

            step(xa1); step(xa2); step(xa3); step(xa4);
            step(xa5); step(xa6); step(xa7); step(xa0);

            mx = pkmax(mx, sh1);
            const uint32_t sh2 = (uint32_t)__shfl_xor((int)mx, 32);
            hp[3] = isq3 ? yb0 : hp[3];   // second half's step-0 x

            step(yb1); step(yb2);

            // ---- finish sample -> NEXT window's scale/fac, in the MFMA
            // shadow (sh2 has had ~2 steps of latency cover) ----
            mx = pkmax(mx, sh2);
            const uint32_t e16 = max(mx & 0xFFFFu, mx >> 16);   // f16-order-isomorphic
            const int pend2 = min(max(25 - (int)(e16 >> 10), 1), 20);
            const int xinv2 = xinv_e + pend2 - 15;
            const float fac2 = __uint_as_float((uint32_t)(127 + xinv2) << 23);

            step(yb3); step(yb4);

            // ---- NEXT window's first-half x, in the shadow ----
            const uint32_t nxa0 = pkrtz(xv0.x * fac2, 0.f);
            const uint32_t nxa1 = pkrtz(xv0.y * fac2, 0.f);
            const uint32_t nxa2 = pkrtz(xv0.z * fac2, 0.f);
            const uint32_t nxa3 = pkrtz(xv0.w * fac2, 0.f);
            const uint32_t nxa4 = pkrtz(xv1.x * fac2, 0.f);
            const uint32_t nxa5 = pkrtz(xv1.y * fac2, 0.f);
            const uint32_t nxa6 = pkrtz(xv1.z * fac2, 0.f);
            const uint32_t nxa7 = pkrtz(xv1.w * fac2, 0.f);

            step(yb5); step(yb6);

            // ---- NEXT window's second-half x, in the shadow ----
            const uint32_t nyb0 = pkrtz(xw0.x * fac2, 0.f);
            const uint32_t nyb1 = pkrtz(xw0.y * fac2, 0.f);
            const uint32_t nyb2 = pkrtz(xw0.z * fac2, 0.f);
            const uint32_t nyb3 = pkrtz(xw0.w * fac2, 0.f);
            const uint32_t nyb4 = pkrtz(xw1.x * fac2, 0.f);
            const uint32_t nyb5 = pkrtz(xw1.y * fac2, 0.f);
            const uint32_t nyb6 = pkrtz(xw1.z * fac2, 0.f);
            const uint32_t nyb7 = pkrtz(xw1.w * fac2, 0.f);

            step(yb7); step(yb0);

            // ---- true boundary: APPLY scale (same point as before -- the
            // state entering window t16+1), rotate x regs, prefetch raw ----
            const uint32_t sc32 = (uint32_t)pend2 * 0x04000400u;  // f16x2 2^(field-15)
            #pragma unroll
            for (int p = 0; p < 4; ++p) hp[p] = scale_mul(hp[p], sc32);
            #pragma unroll
            for (int p = 0; p < 4; ++p) bSp[p] = scale_mul(bSp[p], sc32);
            xinv_e = xinv2;

            xa0 = nxa0; xa1 = nxa1; xa2 = nxa2; xa3 = nxa3;
            xa4 = nxa4; xa5 = nxa5; xa6 = nxa6; xa7 = nxa7;
            yb0 = nyb0; yb1 = nyb1; yb2 = nyb2; yb3 = nyb3;
            yb4 = nyb4; yb5 = nyb5; yb6 = nyb6; yb7 = nyb7;

            // raw x for window t16+2 (dummy in-range reads past the stage end;
            // t16=6's generated values are overwritten at the next stage top)
            const int tnext = (t16 < 5) ? (t16 + 2) * 16 : 0;
            xv0 = *(const float4*)(xrow + tnext);
            xv1 = *(const float4*)(xrow + tnext + 4);
            xw0 = *(const float4*)(xrow + tnext + 8);
            xw1 = *(const float4*)(xrow + tnext + 12);
        }
        __syncthreads();
    }

    // ---- final linear: logits = S * (h_hat @ W_lin^T) + b_lin, S = 2^(-xinv_e) ----
    const float S = __uint_as_float((uint32_t)(127 - xinv_e) << 23);
    float hf[8];
    #pragma unroll
    for (int p = 0; p < 4; ++p) {
        const f16x2 v = __builtin_bit_cast(f16x2, hp[p]);
        hf[2 * p] = (float)v.x;
        hf[2 * p + 1] = (float)v.y;
    }
    float acc[NCLS];
    #pragma unroll
    for (int c = 0; c < NCLS; ++c) {
        float p = 0.f;
        #pragma unroll
        for (int k = 0; k < 8; ++k) {
            const int j = 8 * q + k;
            if (j < HID) p += W_lin[c * HID + j] * hf[k];
        }
        p += __shfl_xor(p, 16, 64);
        p += __shfl_xor(p, 32, 64);
        acc[c] = p * S + b_lin[c];
    }
    if (q == 0) {
        #pragma unroll
        for (int c = 0; c < NCLS; ++c)
            out[(size_t)(b0 + n) * NCLS + c] = acc[c];
    }
}

extern "C" void kernel_launch(void* const* d_in, const int* in_sizes, int n_in,
                              void* d_out, int out_size, void* d_ws, size_t ws_size,
                              hipStream_t stream) {
    const float* inp   = (const float*)d_in[0];
    const float* W_ih  = (const float*)d_in[1];
    const float* W_hh  = (const float*)d_in[2];
    const float* b_mod = (const float*)d_in[3];
    const float* W_lin = (const float*)d_in[4];
    const float* b_lin = (const float*)d_in[5];
    float* out = (float*)d_out;

    dim3 grid(NBATCH / 16);  // 1024 blocks x 1 wave, 16 batch rows each
    dim3 block(64);
    hipLaunchKernelGGL(rnn_scan_kernel, grid, block, 0, stream,
                       inp, W_ih, W_hh, b_mod, W_lin, b_lin, out);
}

// Round 14
// 177.278 us; speedup vs baseline: 1.0155x; 1.0155x over previous
//
#include <hip/hip_runtime.h>
#include <stdint.h>

#define HID 30
#define NCLS 10
#define SEQ 784
#define NBATCH 16384
#define TCH 112      // time steps per LDS stage
#define NSTAGE 7     // 7 * 112 = 784
#define XPAD 116     // padded LDS row stride in floats

typedef _Float16 f16x8 __attribute__((ext_vector_type(8)));
typedef _Float16 f16x2 __attribute__((ext_vector_type(2)));
typedef float f32x4 __attribute__((ext_vector_type(4)));
typedef uint32_t u32x4 __attribute__((ext_vector_type(4)));

static __device__ __forceinline__ f16x8 mkfrag16(uint32_t a, uint32_t b, uint32_t c, uint32_t d) {
    u32x4 t = {a, b, c, d};
    return __builtin_bit_cast(f16x8, t);
}

static __device__ __forceinline__ uint32_t pkf16(_Float16 lo, _Float16 hi) {
    f16x2 v = {lo, hi};
    return __builtin_bit_cast(uint32_t, v);
}

// RNE f32->f16 pair pack. RNE is REQUIRED on the recurrent path (R8: RTZ+bias
// compensation diverged 100x).
static __device__ __forceinline__ uint32_t pk_rne(float a, float b) {
    return pkf16((_Float16)a, (_Float16)b);
}

// RTZ fine for one-shot x injection (non-recurrent)
static __device__ __forceinline__ uint32_t pkrtz(float a, float b) {
    return __builtin_bit_cast(uint32_t, __builtin_amdgcn_cvt_pkrtz(a, b));
}

// packed modReLU on an f16 pair: h = sign(z) * max(|z| + b, 0)
static __device__ __forceinline__ uint32_t modrelu_pk(uint32_t z, uint32_t bp) {
    const f16x2 zero2 = {(_Float16)0.f, (_Float16)0.f};
    f16x2 t = __builtin_bit_cast(f16x2, z & 0x7FFF7FFFu) + __builtin_bit_cast(f16x2, bp);
    t = __builtin_elementwise_max(t, zero2);
    const uint32_t tb = __builtin_bit_cast(uint32_t, t);
    return (tb & 0x7FFF7FFFu) | (z & 0x80008000u);   // -> v_bfi_b32
}

static __device__ __forceinline__ uint32_t pkmax(uint32_t a, uint32_t b) {
    return __builtin_bit_cast(uint32_t,
        __builtin_elementwise_max(__builtin_bit_cast(f16x2, a), __builtin_bit_cast(f16x2, b)));
}

static __device__ __forceinline__ uint32_t scale_mul(uint32_t v, uint32_t sc32) {
    return __builtin_bit_cast(uint32_t,
        __builtin_bit_cast(f16x2, v) * __builtin_bit_cast(f16x2, sc32));
}

// R19 = exact restore of R14 (round 7: 109.4-110.4us/dispatch, 177.8us bench,
// absmax 1.644e30 = baseline-exact, VGPR 56) -- the session's best verified
// kernel. Final banking round; no experiment.
//
// SESSION FLOOR ANALYSIS (R10-R18, all measured): wall = 784 serial steps x
// ~337 cy. Step critical path = 2 chained-MFMA result latencies (the 2-way
// f16 weight split is numerics-REQUIRED -- R16 failed at 1 level) + dependent
// convert/activate tail. VALU shadow is saturated (R15 boundary-dissolve:
// flat). Escapes measured dead: 2-chain ILP (R10, issue-capped), diluted TLP
// (R11, per-wave cost invariant), MFMA de-chain (R12, regressed -- C-chaining
// is HW-forwarded), cooperative 2-wave split (R13, sync > stall), MFMA cut
// (R16, numerics), vector-state codegen (R17, miscompile). Codegen rules:
// hot state = named scalars / const-indexed arrays only; nothing
// address-taken (R9), nothing vector-subscript-written (R17).
__launch_bounds__(64, 1)
__global__ void rnn_scan_kernel(const float* __restrict__ inp,
                                const float* __restrict__ W_ih,
                                const float* __restrict__ W_hh,
                                const float* __restrict__ b_mod,
                                const float* __restrict__ W_lin,
                                const float* __restrict__ b_lin,
                                float* __restrict__ out)
{
    __shared__ __align__(16) float xs_lds[16 * XPAD];

    const int lane = threadIdx.x;   // one wave per block
    const int q = lane >> 4;        // k-quad: lane holds k = 8q..8q+7 of A/B frags
    const int n = lane & 15;        // batch column within the wave's 16-batch tile
    const int b0 = blockIdx.x * 16;

    // ---- A fragments: W_aug [32x32], row-permuted so D->B is lane-local ----
    // W_aug[i][j] = W_hh[i][j] (i,j<30); W_aug[i][30] = W_ih[i]; else 0.
    // A = Ah + Am (2-way f16 RNE split, ~21-bit; weight error systematic)
    const int i1 = 8 * (n >> 2) + (n & 3);
    const int i2 = i1 + 4;

    uint32_t a1h[4], a1m[4], a2h[4], a2m[4];
    #pragma unroll
    for (int p = 0; p < 4; ++p) {
        _Float16 h1[2], m1[2], h2[2], m2[2];
        #pragma unroll
        for (int e = 0; e < 2; ++e) {
            const int j = 8 * q + 2 * p + e;
            float w1 = 0.f, w2 = 0.f;
            if (j < HID) {
                w1 = W_hh[i1 * HID + j];
                if (i2 < HID) w2 = W_hh[i2 * HID + j];
            } else if (j == HID) {
                w1 = W_ih[i1];
                if (i2 < HID) w2 = W_ih[i2];
            }
            h1[e] = (_Float16)w1; m1[e] = (_Float16)(w1 - (float)h1[e]);
            h2[e] = (_Float16)w2; m2[e] = (_Float16)(w2 - (float)h2[e]);
        }
        a1h[p] = pkf16(h1[0], h1[1]); a1m[p] = pkf16(m1[0], m1[1]);
        a2h[p] = pkf16(h2[0], h2[1]); a2m[p] = pkf16(m2[0], m2[1]);
    }
    const f16x8 A1h = mkfrag16(a1h[0], a1h[1], a1h[2], a1h[3]);
    const f16x8 A1m = mkfrag16(a1m[0], a1m[1], a1m[2], a1m[3]);
    const f16x8 A2h = mkfrag16(a2h[0], a2h[1], a2h[2], a2h[3]);
    const f16x8 A2m = mkfrag16(a2m[0], a2m[1], a2m[2], a2m[3]);

    // b_mod packed pairs for this lane's 8 output rows (f16, scaled space b/S)
    uint32_t bSp[4];
    #pragma unroll
    for (int p = 0; p < 4; ++p) {
        const int ja = 8 * q + 2 * p;
        const int jb = ja + 1;
        const float ba = (ja < HID) ? b_mod[ja] : 0.f;
        const float bb = (jb < HID) ? b_mod[jb] : 0.f;
        bSp[p] = pk_rne(ba, bb);
    }

    // packed f16 state: hp[p] = (h[8q+2p], h[8q+2p+1]) in scaled space.
    // True h = S * h_hat, S = 2^(-xinv_e) per column. q3's hp[3] (rows 30,31 =
    // zero rows of W_aug) is dead state, reused as the x-injection slot so the
    // persistent state quad IS the MFMA B fragment.
    uint32_t hp[4] = {0u, 0u, 0u, 0u};
    int xinv_e = 0;
    int pend_field = 15;   // pending scale sc = 2^(field-15); identity for window 0

    const bool isq3 = (q == 3);
    const f32x4 z4 = {0.f, 0.f, 0.f, 0.f};

    // one recurrence step (R0-verbatim chained-MFMA body); xnext = the x value
    // injected into the dead slot for the NEXT step (by value, named scalar).
    auto step = [&](uint32_t xnext) {
        const f16x8 Bh = mkfrag16(hp[0], hp[1], hp[2], hp[3]);
        f32x4 d1 = __builtin_amdgcn_mfma_f32_16x16x32_f16(A1h, Bh, z4, 0, 0, 0);
        f32x4 d2 = __builtin_amdgcn_mfma_f32_16x16x32_f16(A2h, Bh, z4, 0, 0, 0);
        d1 = __builtin_amdgcn_mfma_f32_16x16x32_f16(A1m, Bh, d1, 0, 0, 0);
        d2 = __builtin_amdgcn_mfma_f32_16x16x32_f16(A2m, Bh, d2, 0, 0, 0);
        hp[0] = modrelu_pk(pk_rne(d1[0], d1[1]), bSp[0]);
        hp[1] = modrelu_pk(pk_rne(d1[2], d1[3]), bSp[1]);
        hp[2] = modrelu_pk(pk_rne(d2[0], d2[1]), bSp[2]);
        const uint32_t mr3 = modrelu_pk(pk_rne(d2[2], d2[3]), bSp[3]);
        hp[3] = isq3 ? xnext : mr3;
    };

    // 8 steps; x0 was pre-injected, last step's injection (x0) is a dummy that
    // the next half's pre-injection overwrites.
    auto do8 = [&](uint32_t x0, uint32_t x1, uint32_t x2, uint32_t x3,
                   uint32_t x4, uint32_t x5, uint32_t x6, uint32_t x7) {
        step(x1); step(x2); step(x3); step(x4);
        step(x5); step(x6); step(x7); step(x0);
    };

    for (int s = 0; s < NSTAGE; ++s) {
        // ---- stage TCH steps of inputs for 16 batch rows into LDS ----
        #pragma unroll
        for (int r = 0; r < 7; ++r) {
            const int idx = r * 64 + lane;
            const int bl = idx / 28;
            const int t4 = idx % 28;
            const float4 v = *(const float4*)(inp + (size_t)(b0 + bl) * SEQ + s * TCH + t4 * 4);
            *(float4*)(&xs_lds[bl * XPAD + t4 * 4]) = v;
        }
        __syncthreads();

        const float* xrow = &xs_lds[n * XPAD];
        // xv = first-half x, xw = second-half x of the CURRENT window
        float4 xv0 = *(const float4*)(xrow);
        float4 xv1 = *(const float4*)(xrow + 4);
        float4 xw0 = *(const float4*)(xrow + 8);
        float4 xw1 = *(const float4*)(xrow + 12);

        for (int t16 = 0; t16 < 7; ++t16) {   // 7 * 16 = 112 steps per stage
            // ---- APPLY pending scale (computed from state 16 steps ago) ----
            const uint32_t sc32 = (uint32_t)pend_field * 0x04000400u;  // f16x2 2^(field-15)
            #pragma unroll
            for (int p = 0; p < 4; ++p) hp[p] = scale_mul(hp[p], sc32);
            #pragma unroll
            for (int p = 0; p < 4; ++p) bSp[p] = scale_mul(bSp[p], sc32);
            xinv_e += pend_field - 15;

            // x scale into state space (constant for the whole 16-step window)
            const float fac = __uint_as_float((uint32_t)(127 + xinv_e) << 23);

            // ---- pack BOTH halves' x at window start (data already in regs;
            // 32 independent ops the scheduler spreads across the MFMA shadow)
            const uint32_t xa0 = pkrtz(xv0.x * fac, 0.f);
            const uint32_t xa1 = pkrtz(xv0.y * fac, 0.f);
            const uint32_t xa2 = pkrtz(xv0.z * fac, 0.f);
            const uint32_t xa3 = pkrtz(xv0.w * fac, 0.f);
            const uint32_t xa4 = pkrtz(xv1.x * fac, 0.f);
            const uint32_t xa5 = pkrtz(xv1.y * fac, 0.f);
            const uint32_t xa6 = pkrtz(xv1.z * fac, 0.f);
            const uint32_t xa7 = pkrtz(xv1.w * fac, 0.f);
            const uint32_t y0 = pkrtz(xw0.x * fac, 0.f);
            const uint32_t y1 = pkrtz(xw0.y * fac, 0.f);
            const uint32_t y2 = pkrtz(xw0.z * fac, 0.f);
            const uint32_t y3 = pkrtz(xw0.w * fac, 0.f);
            const uint32_t y4 = pkrtz(xw1.x * fac, 0.f);
            const uint32_t y5 = pkrtz(xw1.y * fac, 0.f);
            const uint32_t y6 = pkrtz(xw1.z * fac, 0.f);
            const uint32_t y7 = pkrtz(xw1.w * fac, 0.f);

            // ---- prefetch NEXT window's x (both halves); LDS latency hides
            // under the 16 steps below. Last window: dummy in-range reads.
            const int tnext = (t16 < 6) ? (t16 + 1) * 16 : 0;
            xv0 = *(const float4*)(xrow + tnext);
            xv1 = *(const float4*)(xrow + tnext + 4);
            xw0 = *(const float4*)(xrow + tnext + 8);
            xw1 = *(const float4*)(xrow + tnext + 12);

            // inject step-0 x, then SAMPLE max for the NEXT window (16-step
            // staleness safe: overflow needs ~2^20 growth in 16 steps,
            // measured ~2^2). Butterfly split: each shfl issues ~8 steps
            // before its consumer so DS latency hides under do8.
            hp[3] = isq3 ? xa0 : hp[3];
            uint32_t mx = pkmax(pkmax(hp[0] & 0x7FFF7FFFu, hp[1] & 0x7FFF7FFFu),
                                pkmax(hp[2] & 0x7FFF7FFFu, hp[3] & 0x7FFF7FFFu));
            const uint32_t sh1 = (uint32_t)__shfl_xor((int)mx, 16);

            do8(xa0, xa1, xa2, xa3, xa4, xa5, xa6, xa7);

            mx = pkmax(mx, sh1);
            const uint32_t sh2 = (uint32_t)__shfl_xor((int)mx, 32);

            hp[3] = isq3 ? y0 : hp[3];   // second half's step-0 x

            do8(y0, y1, y2, y3, y4, y5, y6, y7);

            // finish butterfly, derive next window's pending scale field
            mx = pkmax(mx, sh2);
            // positive f16 bit patterns are order-isomorphic to values
            const uint32_t e16 = max(mx & 0xFFFFu, mx >> 16);
            const int e_raw = (int)(e16 >> 10);             // f16 exponent field
            // target max -> [2^-5, 2^-4): sc = 2^(10-e_raw); clamp [2^-14, 2^5]
            pend_field = min(max(25 - e_raw, 1), 20);
        }
        __syncthreads();
    }

    // ---- final linear: logits = S * (h_hat @ W_lin^T) + b_lin, S = 2^(-xinv_e) ----
    const float S = __uint_as_float((uint32_t)(127 - xinv_e) << 23);
    float hf[8];
    #pragma unroll
    for (int p = 0; p < 4; ++p) {
        const f16x2 v = __builtin_bit_cast(f16x2, hp[p]);
        hf[2 * p] = (float)v.x;
        hf[2 * p + 1] = (float)v.y;
    }
    float acc[NCLS];
    #pragma unroll
    for (int c = 0; c < NCLS; ++c) {
        float p = 0.f;
        #pragma unroll
        for (int k = 0; k < 8; ++k) {
            const int j = 8 * q + k;
            if (j < HID) p += W_lin[c * HID + j] * hf[k];
        }
        p += __shfl_xor(p, 16, 64);
        p += __shfl_xor(p, 32, 64);
        acc[c] = p * S + b_lin[c];
    }
    if (q == 0) {
        #pragma unroll
        for (int c = 0; c < NCLS; ++c)
            out[(size_t)(b0 + n) * NCLS + c] = acc[c];
    }
}

extern "C" void kernel_launch(void* const* d_in, const int* in_sizes, int n_in,
                              void* d_out, int out_size, void* d_ws, size_t ws_size,
                              hipStream_t stream) {
    const float* inp   = (const float*)d_in[0];
    const float* W_ih  = (const float*)d_in[1];
    const float* W_hh  = (const float*)d_in[2];
    const float* b_mod = (const float*)d_in[3];
    const float* W_lin = (const float*)d_in[4];
    const float* b_lin = (const float*)d_in[5];
    float* out = (float*)d_out;

    dim3 grid(NBATCH / 16);  // 1024 blocks x 1 wave, 16 batch rows each
    dim3 block(64);
    hipLaunchKernelGGL(rnn_scan_kernel, grid, block, 0, stream,
                       inp, W_ih, W_hh, b_mod, W_lin, b_lin, out);
}